// Round 13
// baseline (103.586 us; speedup 1.0000x reference)
//
#include <hip/hip_runtime.h>
#include <hip/hip_bf16.h>

#define NNODES 50000
#define KNBR   17
#define DF     128
#define NEDGE  (NNODES*KNBR)
#define BN_EPS 1e-5f
#define SLOPE  0.01f
#define NPAD   50048
#define NBG    ((NNODES+63)/64)      // 782 gemm blocks
#define NBA    (NNODES/8)            // 6250 attn blocks (4 waves x 2 nodes/wave)

// ---- workspace layout (in 4B words) ----
#define NBLK_BN 256
#define OFF_PART 0                            // 256 blocks * 256 floats
#define OFF_SS   (NBLK_BN*256)                // folded biases: b't[128], b'o[128]
#define OFF_WCV  (OFF_SS + 256)               // Wcv: 256 cols x 64 uints (bf16 pairs, sc-folded)
#define OFF_HBF  (OFF_WCV + 256*64)           // Hbf: NPAD rows x 64 uints (128 bf16 of raw H)
#define OFF_T    (OFF_HBF + NPAD*64)          // T32: NPAD rows x 64 uints (128 fp16 of Ht)
#define OFF_Y    (OFF_T + NPAD*64)            // Y32: NPAD rows x 64 uints (128 fp16 of Out)

typedef __fp16  h2_t   __attribute__((ext_vector_type(2)));
typedef short   short8 __attribute__((ext_vector_type(8)));
typedef float   f32x4  __attribute__((ext_vector_type(4)));
typedef float   f32x2  __attribute__((ext_vector_type(2)));

__device__ __forceinline__ unsigned pack2bf(float x, float y) {
    __hip_bfloat16 a = __float2bfloat16(x), b = __float2bfloat16(y);
    unsigned short ua = __builtin_bit_cast(unsigned short, a);
    unsigned short ub = __builtin_bit_cast(unsigned short, b);
    return (unsigned)ua | ((unsigned)ub << 16);
}
__device__ __forceinline__ unsigned pack2h(float x, float y) {
    auto h = __builtin_amdgcn_cvt_pkrtz(x, y);
    return __builtin_bit_cast(unsigned, h);
}

// ---- K1: BN stats + H -> bf16 cast (raw H; BN gets folded into W later) -----
__global__ __launch_bounds__(256) void bn_stats_hcast(const float* __restrict__ H,
                                                      float* __restrict__ part,
                                                      unsigned* __restrict__ Hbf) {
    const int tid = threadIdx.x;
    const int cg = tid & 31;
    const int rg = tid >> 5;
    const float4* H4 = (const float4*)H;
    float4 s = {0,0,0,0}, q = {0,0,0,0};
    for (int r = blockIdx.x*8 + rg; r < NNODES; r += NBLK_BN*8) {
        float4 v = H4[r*32 + cg];
        s.x += v.x; s.y += v.y; s.z += v.z; s.w += v.w;
        q.x = fmaf(v.x, v.x, q.x); q.y = fmaf(v.y, v.y, q.y);
        q.z = fmaf(v.z, v.z, q.z); q.w = fmaf(v.w, v.w, q.w);
        uint2 pk = { pack2bf(v.x, v.y), pack2bf(v.z, v.w) };
        *(uint2*)&Hbf[(size_t)r*64 + 2*cg] = pk;
    }
    __shared__ float red[8][32][8];
    red[rg][cg][0] = s.x; red[rg][cg][1] = s.y; red[rg][cg][2] = s.z; red[rg][cg][3] = s.w;
    red[rg][cg][4] = q.x; red[rg][cg][5] = q.y; red[rg][cg][6] = q.z; red[rg][cg][7] = q.w;
    __syncthreads();
    float v = 0.f;
    const int cg2 = tid >> 3, slot = tid & 7;
    #pragma unroll
    for (int g = 0; g < 8; ++g) v += red[g][cg2][slot];
    part[blockIdx.x*256 + tid] = v;
}

// ---- K2: finalize stats; fold BN into W (bf16 Wcv) and biases (ss) ----------
__global__ __launch_bounds__(256) void bn_fold(const float* __restrict__ part,
                                               const float* __restrict__ gamma,
                                               const float* __restrict__ beta,
                                               const float* __restrict__ Wt,
                                               const float* __restrict__ bt,
                                               const float* __restrict__ Wo,
                                               const float* __restrict__ bo,
                                               float* __restrict__ ssOut,
                                               unsigned* __restrict__ Wcv) {
    __shared__ float tot[256];
    __shared__ float sc_s[128], sh_s[128];
    const int t = threadIdx.x;
    float v = 0.f;
    for (int b = 0; b < NBLK_BN; ++b) v += part[b*256 + t];
    tot[t] = v;
    __syncthreads();
    if (t < 128) {
        const int cg = t >> 2, sl = t & 3;
        const float sum = tot[cg*8 + sl];
        const float sq  = tot[cg*8 + 4 + sl];
        const float mean = sum * (1.0f/NNODES);
        const float var  = sq * (1.0f/NNODES) - mean*mean;
        const float sc = rsqrtf(var + BN_EPS) * gamma[t];
        sc_s[t] = sc;
        sh_s[t] = beta[t] - mean*sc;
    }
    __syncthreads();
    // scale W rows by sc -> bf16 pairs; fold shift into bias
    const int tab = t >> 7, c = t & 127;
    const float* W  = tab ? Wo : Wt;
    const float* bi = tab ? bo : bt;
    unsigned* dst = Wcv + tab*128*64;
    float bacc = bi[c];
    #pragma unroll 8
    for (int kp = 0; kp < 64; ++kp) {
        const float w0 = W[(size_t)(2*kp)*128 + c];
        const float w1 = W[(size_t)(2*kp+1)*128 + c];
        dst[c*64 + kp] = pack2bf(sc_s[2*kp]*w0, sc_s[2*kp+1]*w1);
        bacc = fmaf(sh_s[2*kp], w0, fmaf(sh_s[2*kp+1], w1, bacc));
    }
    ssOut[t] = bacc;        // [0..127]=b't, [128..255]=b'o
}

// ---- K3: MFMA bf16 dual GEMM (raw Hbf x folded W) -> fp16 tables T, Y -------
__global__ __launch_bounds__(256) void dual_gemm_mfma(const unsigned* __restrict__ Hbf,
                                                      const float* __restrict__ ss,
                                                      const unsigned* __restrict__ Wcv,
                                                      unsigned* __restrict__ T32,
                                                      unsigned* __restrict__ Y32) {
    __shared__ short As[64][48];
    __shared__ short Bs[256][48];
    const int tid  = threadIdx.x;
    const int lane = tid & 63;
    const int wc   = tid >> 6;
    const int row0 = blockIdx.x * 64;

    f32x4 acc[4][4];
    #pragma unroll
    for (int a = 0; a < 4; ++a)
        #pragma unroll
        for (int b = 0; b < 4; ++b) acc[a][b] = (f32x4){0,0,0,0};

    const int lrow = lane & 15, lk = lane >> 4;

    for (int s = 0; s < 4; ++s) {
        __syncthreads();
        { // stage A: pure 16B copies of raw Hbf
            const int r = tid >> 2, cq = tid & 3;
            const int row = row0 + r;
            uint4 aw = {0,0,0,0};
            if (row < NNODES) aw = *(const uint4*)&Hbf[(size_t)row*64 + s*16 + cq*4];
            const int g = cq ^ ((r >> 2) & 3);
            *(uint4*)&As[r][g*8] = aw;
        }
        { // stage B: pure 16B copies of folded Wcv
            const int c  = tid;
            const unsigned* src = Wcv + c*64 + s*16;
            const int xr = (c >> 2) & 3;
            #pragma unroll
            for (int g = 0; g < 4; ++g)
                *(uint4*)&Bs[c][(g ^ xr)*8] = *(const uint4*)&src[g*4];
        }
        __syncthreads();
        short8 af[4], bf[4];
        #pragma unroll
        for (int mt = 0; mt < 4; ++mt) {
            const int r = mt*16 + lrow;
            const int g = lk ^ ((r >> 2) & 3);
            af[mt] = *(const short8*)&As[r][g*8];
        }
        #pragma unroll
        for (int nt = 0; nt < 4; ++nt) {
            const int cr = wc*64 + nt*16 + lrow;
            const int g  = lk ^ ((cr >> 2) & 3);
            bf[nt] = *(const short8*)&Bs[cr][g*8];
        }
        #pragma unroll
        for (int mt = 0; mt < 4; ++mt)
            #pragma unroll
            for (int nt = 0; nt < 4; ++nt)
                acc[mt][nt] = __builtin_amdgcn_mfma_f32_16x16x32_bf16(
                    af[mt], bf[nt], acc[mt][nt], 0, 0, 0);
    }

    // epilogue: +folded bias, pack fp16 col-pairs via shfl_xor(1), store dwords
    const bool isY = (wc >= 2);
    unsigned* dstT = isY ? Y32 : T32;
    const float* bias = ss + (isY ? 128 : 0);
    float bv[4];
    #pragma unroll
    for (int nt = 0; nt < 4; ++nt)
        bv[nt] = bias[(wc & 1)*64 + nt*16 + lrow];
    const int isodd = lane & 1;
    const int cp8   = (lane & 15) >> 1;
    #pragma unroll
    for (int mt = 0; mt < 4; ++mt) {
        #pragma unroll
        for (int ntp = 0; ntp < 2; ++ntp) {
            const int ntA = 2*ntp, ntB = ntA + 1;
            #pragma unroll
            for (int reg = 0; reg < 4; ++reg) {
                const float a = acc[mt][ntA][reg] + bv[ntA];
                const float b = acc[mt][ntB][reg] + bv[ntB];
                const float send = isodd ? a : b;
                const float got  = __shfl_xor(send, 1);
                const float lo = isodd ? got : a;
                const float hi = isodd ? b   : got;
                const unsigned pk = pack2h(lo, hi);
                const int nte = ntA + isodd;
                const int row = row0 + mt*16 + (lane >> 4)*4 + reg;
                const int dw  = 32*(wc & 1) + 8*nte + cp8;
                if (row < NNODES) dstT[(size_t)row*64 + dw] = pk;
            }
        }
    }
}

// ---- K4: fused scores+softmax+agg (2 nodes/wave; phased gathers) ------------
__device__ __forceinline__ float merge2(float A, float B, int lane, int m) {
    const bool hi = (lane & m) != 0;
    float t = hi ? A : B;
    t = __shfl_xor(t, m);
    return (hi ? B : A) + t;
}

__global__ __launch_bounds__(256, 4) void attn_fused(const unsigned* __restrict__ T32,
                                                     const unsigned* __restrict__ Y32,
                                                     const int* __restrict__ col,
                                                     float* __restrict__ Aout,
                                                     float* __restrict__ outF) {
    const int tid   = threadIdx.x;
    const int lane  = tid & 63;
    const int wg    = (blockIdx.x*256 + tid) >> 6;   // 25000 waves, exact
    const int s2    = lane & 31;
    const int hbase = lane & 32;
    const int i     = wg*2 + (lane >> 5);            // node per half-wave
    const uint2* T2 = (const uint2*)T32;
    const uint2* Y2 = (const uint2*)Y32;

    const uint2 av = T2[(size_t)i*32 + s2];
    const h2_t a0 = __builtin_bit_cast(h2_t, av.x);
    const h2_t a1 = __builtin_bit_cast(h2_t, av.y);

    int myj = 0;
    if (s2 < KNBR) myj = col[i*KNBR + s2];

    // broadcast all 17 neighbor indices
    int jj[KNBR];
    #pragma unroll
    for (int k = 0; k < KNBR; ++k) jj[k] = __shfl(myj, hbase | k);

    // phase A: T gathers -> dots
    float p[KNBR];
    {
        uint2 v[KNBR];
        #pragma unroll
        for (int k = 0; k < KNBR; ++k) v[k] = T2[(size_t)jj[k]*32 + s2];
        #pragma unroll
        for (int k = 0; k < KNBR; ++k)
            p[k] = __builtin_amdgcn_fdot2(a1, __builtin_bit_cast(h2_t, v[k].y),
                   __builtin_amdgcn_fdot2(a0, __builtin_bit_cast(h2_t, v[k].x), 0.0f, false), false);
    }

    // merge tree within each 32-lane half (masks 1..16)
    float q0 = merge2(p[0],  p[1],  lane, 1);
    float q1 = merge2(p[2],  p[3],  lane, 1);
    float q2 = merge2(p[4],  p[5],  lane, 1);
    float q3 = merge2(p[6],  p[7],  lane, 1);
    float q4 = merge2(p[8],  p[9],  lane, 1);
    float q5 = merge2(p[10], p[11], lane, 1);
    float q6 = merge2(p[12], p[13], lane, 1);
    float q7 = merge2(p[14], p[15], lane, 1);
    float q8 = p[16] + __shfl_xor(p[16], 1);

    float r0 = merge2(q0, q1, lane, 2);
    float r1 = merge2(q2, q3, lane, 2);
    float r2 = merge2(q4, q5, lane, 2);
    float r3 = merge2(q6, q7, lane, 2);
    float r4 = q8 + __shfl_xor(q8, 2);

    float s0 = merge2(r0, r1, lane, 4);
    float s1 = merge2(r2, r3, lane, 4);
    float s2f = r4 + __shfl_xor(r4, 4);

    float t0 = merge2(s0, s1, lane, 8);
    float t1 = s2f + __shfl_xor(s2f, 8);

    const float u = merge2(t0, t1, lane, 16);
    // lane s2 holds dot[k], k = (s2&16) ? 16 : (s2&15)

    const float sig = 1.0f / (1.0f + __expf(-u));
    const float e   = __expf(sig);
    const float me  = (s2 < KNBR) ? e : 0.0f;
    float S = me;
    S += __shfl_xor(S, 1);  S += __shfl_xor(S, 2);  S += __shfl_xor(S, 4);
    S += __shfl_xor(S, 8);  S += __shfl_xor(S, 16);
    const float Alane = e / S;
    if (s2 < KNBR) Aout[(size_t)i*KNBR + s2] = Alane;

    // phase B: broadcast weights, Y gathers, weighted accumulate
    const int Abits = __builtin_bit_cast(int, Alane);
    float ak[KNBR];
    #pragma unroll
    for (int k = 0; k < KNBR; ++k)
        ak[k] = __builtin_bit_cast(float, __shfl(Abits, hbase | k));

    uint2 y[KNBR];
    #pragma unroll
    for (int k = 0; k < KNBR; ++k) y[k] = Y2[(size_t)jj[k]*32 + s2];

    f32x4 acc = {0,0,0,0};
    #pragma unroll
    for (int k = 0; k < KNBR; ++k) {
        const h2_t y0 = __builtin_bit_cast(h2_t, y[k].x);
        const h2_t y1 = __builtin_bit_cast(h2_t, y[k].y);
        acc.x = fmaf(ak[k], (float)y0.x, acc.x);
        acc.y = fmaf(ak[k], (float)y0.y, acc.y);
        acc.z = fmaf(ak[k], (float)y1.x, acc.z);
        acc.w = fmaf(ak[k], (float)y1.y, acc.w);
    }
    acc.x = (acc.x >= 0.f) ? acc.x : SLOPE*acc.x;
    acc.y = (acc.y >= 0.f) ? acc.y : SLOPE*acc.y;
    acc.z = (acc.z >= 0.f) ? acc.z : SLOPE*acc.z;
    acc.w = (acc.w >= 0.f) ? acc.w : SLOPE*acc.w;
    __builtin_nontemporal_store(acc, (f32x4*)&outF[(size_t)i*DF + 4*s2]);
}

extern "C" void kernel_launch(void* const* d_in, const int* in_sizes, int n_in,
                              void* d_out, int out_size, void* d_ws, size_t ws_size,
                              hipStream_t stream) {
    const float* H     = (const float*)d_in[0];
    const int*   col   = (const int*)  d_in[1];
    // d_in[2] = row (== e/17 analytically, unused)
    const float* gamma = (const float*)d_in[3];
    const float* beta  = (const float*)d_in[4];
    const float* Wt    = (const float*)d_in[5];
    const float* bt    = (const float*)d_in[6];
    const float* Wo    = (const float*)d_in[7];
    const float* bo    = (const float*)d_in[8];

    float* ws   = (float*)d_ws;
    float* part = ws + OFF_PART;
    float* ss   = ws + OFF_SS;
    unsigned* Wcv = (unsigned*)(ws + OFF_WCV);
    unsigned* Hbf = (unsigned*)(ws + OFF_HBF);
    unsigned* T32 = (unsigned*)(ws + OFF_T);
    unsigned* Y32 = (unsigned*)(ws + OFF_Y);

    float* outF = (float*)d_out;
    float* Aout = outF + (size_t)NNODES*DF;

    bn_stats_hcast<<<dim3(NBLK_BN), dim3(256), 0, stream>>>(H, part, Hbf);
    bn_fold       <<<dim3(1),       dim3(256), 0, stream>>>(part, gamma, beta, Wt, bt, Wo, bo, ss, Wcv);
    dual_gemm_mfma<<<dim3(NBG),     dim3(256), 0, stream>>>(Hbf, ss, Wcv, T32, Y32);
    attn_fused    <<<dim3(NBA),     dim3(256), 0, stream>>>(T32, Y32, col, Aout, outF);
}

// Round 14
// 94.828 us; speedup vs baseline: 1.0924x; 1.0924x over previous
//
#include <hip/hip_runtime.h>
#include <hip/hip_bf16.h>

#define NNODES 50000
#define KNBR   17
#define DF     128
#define NEDGE  (NNODES*KNBR)
#define BN_EPS 1e-5f
#define SLOPE  0.01f
#define NPAD   50048

// ---- workspace layout (in 4B words) ----
#define NBLK_BN 256
#define OFF_PART 0                            // 256 blocks * 256 floats
#define OFF_SS   (NBLK_BN*256)                // scale[128], shift[128]
#define OFF_T    (OFF_SS + 256)               // T32: NPAD rows x 64 uints (128 fp16 of Ht)
#define OFF_Y    (OFF_T + NPAD*64)            // Y32: NPAD rows x 64 uints (128 fp16 of Out)

typedef __fp16  h2_t   __attribute__((ext_vector_type(2)));
typedef short   short8 __attribute__((ext_vector_type(8)));
typedef float   f32x4  __attribute__((ext_vector_type(4)));
typedef float   f32x2  __attribute__((ext_vector_type(2)));

__device__ __forceinline__ unsigned pack2bf(float x, float y) {
    __hip_bfloat16 a = __float2bfloat16(x), b = __float2bfloat16(y);
    unsigned short ua = __builtin_bit_cast(unsigned short, a);
    unsigned short ub = __builtin_bit_cast(unsigned short, b);
    return (unsigned)ua | ((unsigned)ub << 16);
}
__device__ __forceinline__ unsigned pack2h(float x, float y) {
    auto h = __builtin_amdgcn_cvt_pkrtz(x, y);
    return __builtin_bit_cast(unsigned, h);
}

// ---------------- K1: BatchNorm stats (partial sums, no atomics) -------------
__global__ __launch_bounds__(256) void bn_stats(const float* __restrict__ H,
                                                float* __restrict__ part) {
    const int tid = threadIdx.x;
    const int cg = tid & 31;
    const int rg = tid >> 5;
    const float4* H4 = (const float4*)H;
    float4 s = {0,0,0,0}, q = {0,0,0,0};
    for (int r = blockIdx.x*8 + rg; r < NNODES; r += NBLK_BN*8) {
        float4 v = H4[r*32 + cg];
        s.x += v.x; s.y += v.y; s.z += v.z; s.w += v.w;
        q.x = fmaf(v.x, v.x, q.x); q.y = fmaf(v.y, v.y, q.y);
        q.z = fmaf(v.z, v.z, q.z); q.w = fmaf(v.w, v.w, q.w);
    }
    __shared__ float red[8][32][8];
    red[rg][cg][0] = s.x; red[rg][cg][1] = s.y; red[rg][cg][2] = s.z; red[rg][cg][3] = s.w;
    red[rg][cg][4] = q.x; red[rg][cg][5] = q.y; red[rg][cg][6] = q.z; red[rg][cg][7] = q.w;
    __syncthreads();
    float v = 0.f;
    const int cg2 = tid >> 3, slot = tid & 7;
    #pragma unroll
    for (int g = 0; g < 8; ++g) v += red[g][cg2][slot];
    part[blockIdx.x*256 + tid] = v;
}

// ---------------- K2: finalize -> scale/shift --------------------------------
__global__ __launch_bounds__(256) void bn_finalize(const float* __restrict__ part,
                                                   const float* __restrict__ gamma,
                                                   const float* __restrict__ beta,
                                                   float* __restrict__ ss) {
    __shared__ float tot[256];
    const int t = threadIdx.x;
    float v = 0.f;
    for (int b = 0; b < NBLK_BN; ++b) v += part[b*256 + t];
    tot[t] = v;
    __syncthreads();
    if (t < 128) {
        const int cg = t >> 2, sl = t & 3;
        const float sum = tot[cg*8 + sl];
        const float sq  = tot[cg*8 + 4 + sl];
        const float mean = sum * (1.0f/NNODES);
        const float var  = sq * (1.0f/NNODES) - mean*mean;
        const float sc = rsqrtf(var + BN_EPS) * gamma[t];
        ss[t]       = sc;
        ss[128 + t] = beta[t] - mean*sc;
    }
}

// ---- K3: MFMA bf16 dual GEMM -> fp16 tables T (Ht) and Y (Out) --------------
// block 256 thr (4 waves), tile 64M x 256N; wave = 64x64; K-steps of 32.
// LDS layout: [row][48 shorts]; 16B k-group g stored at g ^ ((row>>2)&3).
__global__ __launch_bounds__(256) void dual_gemm_mfma(const float* __restrict__ H,
                                                      const float* __restrict__ ss,
                                                      const float* __restrict__ Wt,
                                                      const float* __restrict__ bt,
                                                      const float* __restrict__ Wo,
                                                      const float* __restrict__ bo,
                                                      unsigned* __restrict__ T32,
                                                      unsigned* __restrict__ Y32) {
    __shared__ short As[64][48];
    __shared__ short Bs[256][48];
    const int tid  = threadIdx.x;
    const int lane = tid & 63;
    const int wc   = tid >> 6;            // 0..3: which 64-col slab
    const int row0 = blockIdx.x * 64;
    const float4* H4  = (const float4*)H;
    const float4* ss4 = (const float4*)ss;

    f32x4 acc[4][4];
    #pragma unroll
    for (int a = 0; a < 4; ++a)
        #pragma unroll
        for (int b = 0; b < 4; ++b) acc[a][b] = (f32x4){0,0,0,0};

    const int lrow = lane & 15, lk = lane >> 4;

    for (int s = 0; s < 4; ++s) {          // K step: k in [32s, 32s+32)
        __syncthreads();
        { // stage A (BN applied, fp32 -> bf16): r=tid>>2, k-group cq=tid&3
            const int r = tid >> 2, cq = tid & 3;
            const int row = row0 + r;
            float4 h0 = {0,0,0,0}, h1 = {0,0,0,0};
            if (row < NNODES) {
                h0 = H4[(size_t)row*32 + s*8 + cq*2];
                h1 = H4[(size_t)row*32 + s*8 + cq*2 + 1];
            }
            const float4 sc0 = ss4[s*8 + cq*2],      sc1 = ss4[s*8 + cq*2 + 1];
            const float4 sh0 = ss4[32 + s*8 + cq*2], sh1 = ss4[32 + s*8 + cq*2 + 1];
            uint4 aw;
            aw.x = pack2bf(fmaf(h0.x, sc0.x, sh0.x), fmaf(h0.y, sc0.y, sh0.y));
            aw.y = pack2bf(fmaf(h0.z, sc0.z, sh0.z), fmaf(h0.w, sc0.w, sh0.w));
            aw.z = pack2bf(fmaf(h1.x, sc1.x, sh1.x), fmaf(h1.y, sc1.y, sh1.y));
            aw.w = pack2bf(fmaf(h1.z, sc1.z, sh1.z), fmaf(h1.w, sc1.w, sh1.w));
            const int g = cq ^ ((r >> 2) & 3);
            *(uint4*)&As[r][g*8] = aw;
        }
        { // stage B: thread c owns col c, all 32 k of this step
            const int c    = tid;
            const int colb = c & 127;
            const float* W = (c & 128) ? Wo : Wt;
            float v[32];
            #pragma unroll
            for (int i = 0; i < 32; ++i)
                v[i] = W[(size_t)(s*32 + i)*128 + colb];
            #pragma unroll
            for (int g = 0; g < 4; ++g) {
                uint4 bw;
                bw.x = pack2bf(v[8*g+0], v[8*g+1]);
                bw.y = pack2bf(v[8*g+2], v[8*g+3]);
                bw.z = pack2bf(v[8*g+4], v[8*g+5]);
                bw.w = pack2bf(v[8*g+6], v[8*g+7]);
                const int gs = g ^ ((c >> 2) & 3);
                *(uint4*)&Bs[c][gs*8] = bw;
            }
        }
        __syncthreads();
        short8 af[4], bf[4];
        #pragma unroll
        for (int mt = 0; mt < 4; ++mt) {
            const int r = mt*16 + lrow;
            const int g = lk ^ ((r >> 2) & 3);
            af[mt] = *(const short8*)&As[r][g*8];
        }
        #pragma unroll
        for (int nt = 0; nt < 4; ++nt) {
            const int cr = wc*64 + nt*16 + lrow;
            const int g  = lk ^ ((cr >> 2) & 3);
            bf[nt] = *(const short8*)&Bs[cr][g*8];
        }
        #pragma unroll
        for (int mt = 0; mt < 4; ++mt)
            #pragma unroll
            for (int nt = 0; nt < 4; ++nt)
                acc[mt][nt] = __builtin_amdgcn_mfma_f32_16x16x32_bf16(
                    af[mt], bf[nt], acc[mt][nt], 0, 0, 0);
    }

    // epilogue: +bias, pack fp16 col-pairs via shfl_xor(1), store dwords
    const bool isY = (wc >= 2);
    unsigned* dstT = isY ? Y32 : T32;
    const float* bias = isY ? bo : bt;
    float bv[4];
    #pragma unroll
    for (int nt = 0; nt < 4; ++nt)
        bv[nt] = bias[(wc & 1)*64 + nt*16 + lrow];
    const int isodd = lane & 1;
    const int cp8   = (lane & 15) >> 1;
    #pragma unroll
    for (int mt = 0; mt < 4; ++mt) {
        #pragma unroll
        for (int ntp = 0; ntp < 2; ++ntp) {
            const int ntA = 2*ntp, ntB = ntA + 1;
            #pragma unroll
            for (int reg = 0; reg < 4; ++reg) {
                const float a = acc[mt][ntA][reg] + bv[ntA];
                const float b = acc[mt][ntB][reg] + bv[ntB];
                const float send = isodd ? a : b;
                const float got  = __shfl_xor(send, 1);
                const float lo = isodd ? got : a;
                const float hi = isodd ? b   : got;
                const unsigned pk = pack2h(lo, hi);
                const int nte = ntA + isodd;
                const int row = row0 + mt*16 + (lane >> 4)*4 + reg;
                const int dw  = 32*(wc & 1) + 8*nte + cp8;
                if (row < NNODES) dstT[(size_t)row*64 + dw] = pk;
            }
        }
    }
}

// ---------------- K4: scores + softmax -> A ----------------------------------
// one 64-lane wave per node; lane l owns col-pair (2l, 2l+1) (one uint)
__device__ __forceinline__ float merge2(float A, float B, int lane, int m) {
    const bool hi = (lane & m) != 0;
    float t = hi ? A : B;
    t = __shfl_xor(t, m);
    return (hi ? B : A) + t;
}

__global__ __launch_bounds__(256) void attn_scores(const unsigned* __restrict__ T32,
                                                   const int* __restrict__ col,
                                                   float* __restrict__ Aout) {
    const int tid  = threadIdx.x;
    const int lane = tid & 63;
    const int i    = (blockIdx.x*256 + tid) >> 6;
    if (i >= NNODES) return;

    const h2_t a = __builtin_bit_cast(h2_t, T32[(size_t)i*64 + lane]);

    int myj = 0;
    if (lane < KNBR) myj = col[i*KNBR + lane];

    float p[KNBR];
    #pragma unroll
    for (int k = 0; k < KNBR; ++k) {
        const int j = __builtin_amdgcn_readlane(myj, k);
        const unsigned v = T32[(size_t)j*64 + lane];
        p[k] = __builtin_amdgcn_fdot2(a, __builtin_bit_cast(h2_t, v), 0.0f, false);
    }

    // merge-tree reduction of 17 wave-wide dots
    float q0 = merge2(p[0],  p[1],  lane, 1);
    float q1 = merge2(p[2],  p[3],  lane, 1);
    float q2 = merge2(p[4],  p[5],  lane, 1);
    float q3 = merge2(p[6],  p[7],  lane, 1);
    float q4 = merge2(p[8],  p[9],  lane, 1);
    float q5 = merge2(p[10], p[11], lane, 1);
    float q6 = merge2(p[12], p[13], lane, 1);
    float q7 = merge2(p[14], p[15], lane, 1);
    float q8 = p[16] + __shfl_xor(p[16], 1);

    float r0 = merge2(q0, q1, lane, 2);
    float r1 = merge2(q2, q3, lane, 2);
    float r2 = merge2(q4, q5, lane, 2);
    float r3 = merge2(q6, q7, lane, 2);
    float r4 = q8 + __shfl_xor(q8, 2);

    float s0 = merge2(r0, r1, lane, 4);
    float s1 = merge2(r2, r3, lane, 4);
    float s2 = r4 + __shfl_xor(r4, 4);

    float t0 = merge2(s0, s1, lane, 8);
    float t1 = s2 + __shfl_xor(s2, 8);

    float u = merge2(t0, t1, lane, 16);
    u += __shfl_xor(u, 32);

    const float sig = 1.0f / (1.0f + __expf(-u));
    const float e   = __expf(sig);
    const float me  = ((lane & 31) < KNBR) ? e : 0.0f;
    float S = me;
    S += __shfl_xor(S, 1);  S += __shfl_xor(S, 2);  S += __shfl_xor(S, 4);
    S += __shfl_xor(S, 8);  S += __shfl_xor(S, 16);
    if (lane < KNBR) Aout[(size_t)i*KNBR + lane] = e / S;
}

// ---------------- K5: A-weighted aggregation + LeakyReLU ---------------------
__global__ __launch_bounds__(256) void attn_agg(const unsigned* __restrict__ Y32,
                                                const int* __restrict__ col,
                                                const float* __restrict__ Aout,
                                                float* __restrict__ outF) {
    const int tid  = threadIdx.x;
    const int lane = tid & 63;
    const int i    = (blockIdx.x*256 + tid) >> 6;
    if (i >= NNODES) return;

    int   myj = 0;
    float myA = 0.f;
    if (lane < KNBR) {
        myj = col[i*KNBR + lane];
        myA = Aout[(size_t)i*KNBR + lane];
    }
    const int Abits = __builtin_bit_cast(int, myA);

    float acc0 = 0.f, acc1 = 0.f;
    #pragma unroll
    for (int k = 0; k < KNBR; ++k) {
        const int j = __builtin_amdgcn_readlane(myj, k);
        const float ak = __builtin_bit_cast(float, __builtin_amdgcn_readlane(Abits, k));
        const h2_t y = __builtin_bit_cast(h2_t, Y32[(size_t)j*64 + lane]);
        acc0 = fmaf(ak, (float)y.x, acc0);
        acc1 = fmaf(ak, (float)y.y, acc1);
    }
    acc0 = (acc0 >= 0.f) ? acc0 : SLOPE*acc0;
    acc1 = (acc1 >= 0.f) ? acc1 : SLOPE*acc1;
    f32x2 o = {acc0, acc1};
    __builtin_nontemporal_store(o, (f32x2*)&outF[(size_t)i*DF + 2*lane]);
}

extern "C" void kernel_launch(void* const* d_in, const int* in_sizes, int n_in,
                              void* d_out, int out_size, void* d_ws, size_t ws_size,
                              hipStream_t stream) {
    const float* H     = (const float*)d_in[0];
    const int*   col   = (const int*)  d_in[1];
    // d_in[2] = row (== e/17 analytically, unused)
    const float* gamma = (const float*)d_in[3];
    const float* beta  = (const float*)d_in[4];
    const float* Wt    = (const float*)d_in[5];
    const float* bt    = (const float*)d_in[6];
    const float* Wo    = (const float*)d_in[7];
    const float* bo    = (const float*)d_in[8];

    float* ws   = (float*)d_ws;
    float* part = ws + OFF_PART;
    float* ss   = ws + OFF_SS;
    unsigned* T32 = (unsigned*)(ws + OFF_T);
    unsigned* Y32 = (unsigned*)(ws + OFF_Y);

    float* outF = (float*)d_out;
    float* Aout = outF + (size_t)NNODES*DF;

    bn_stats      <<<dim3(NBLK_BN), dim3(256), 0, stream>>>(H, part);
    bn_finalize   <<<dim3(1),       dim3(256), 0, stream>>>(part, gamma, beta, ss);
    dual_gemm_mfma<<<dim3((NNODES+63)/64), dim3(256), 0, stream>>>(H, ss, Wt, bt, Wo, bo, T32, Y32);
    attn_scores   <<<dim3((NNODES+3)/4), dim3(256), 0, stream>>>(T32, col, Aout);
    attn_agg      <<<dim3((NNODES+3)/4), dim3(256), 0, stream>>>(Y32, col, Aout, outF);
}